// Round 3
// baseline (85.782 us; speedup 1.0000x reference)
//
#include <hip/hip_runtime.h>
#include <hip/hip_bf16.h>

#define SIZE 128

// Per-element body: 3 hardware trans ops (exp, rcp, log) + ~8 VALU ops.
// var = e^b + 1/(e^{-a} + e^{-lv})  ==>  inv_var = s / (e^b * s + 1),
// s = e^{-a} + e^{-lv};  l2 = log(var) = -log(inv_var)
__device__ __forceinline__ void accum4(float4 m, float4 lv, float4 tg,
                                       const float* __restrict__ ena,
                                       const float* __restrict__ eb,
                                       float& acc) {
    #pragma unroll
    for (int k = 0; k < 4; ++k) {
        float lvk = (&lv.x)[k];
        float d   = (&m.x)[k] - (&tg.x)[k];
        float t   = __expf(-lvk);                          // v_exp_f32
        float s   = ena[k] + t;
        float u   = __builtin_fmaf(eb[k], s, 1.0f);
        float inv = s * __builtin_amdgcn_rcpf(u);          // v_rcp_f32
        float l2  = -__logf(inv);                          // v_log_f32
        acc += d * d * inv + l2;
    }
}

__global__ __launch_bounds__(256) void probloss_kernel(
    const float4* __restrict__ inputs,    // (N, 256) as float4: 64 groups/row
    const float4* __restrict__ targets,   // (N, 128) as float4: 32 groups/row
    const float4* __restrict__ maxlv,     // (128,) as 32 float4
    const float4* __restrict__ minlv,     // (128,) as 32 float4
    float* __restrict__ out,
    int nrows)                            // N
{
    const int gtid    = blockIdx.x * blockDim.x + threadIdx.x;
    const int cg      = gtid & 31;        // fixed column group for this thread
    const int row0    = gtid >> 5;
    const int rstride = (gridDim.x * blockDim.x) >> 5;

    // Hoisted per-column constants: e^{-max_logvar}, e^{min_logvar}
    float4 a = maxlv[cg];
    float4 b = minlv[cg];
    float ena[4], eb[4];
    #pragma unroll
    for (int k = 0; k < 4; ++k) {
        ena[k] = __expf(-(&a.x)[k]);
        eb[k]  = __expf((&b.x)[k]);
    }

    float acc0 = 0.0f, acc1 = 0.0f;
    int r = row0;
    // 2-way unroll: independent load+trans chains per half-iteration
    for (; r + rstride < nrows; r += 2 * rstride) {
        const int r1 = r + rstride;
        float4 m0  = inputs[r  * 64 + cg];
        float4 lv0 = inputs[r  * 64 + 32 + cg];
        float4 tg0 = targets[r  * 32 + cg];
        float4 m1  = inputs[r1 * 64 + cg];
        float4 lv1 = inputs[r1 * 64 + 32 + cg];
        float4 tg1 = targets[r1 * 32 + cg];
        accum4(m0, lv0, tg0, ena, eb, acc0);
        accum4(m1, lv1, tg1, ena, eb, acc1);
    }
    for (; r < nrows; r += rstride) {
        accum4(inputs[r * 64 + cg], inputs[r * 64 + 32 + cg],
               targets[r * 32 + cg], ena, eb, acc0);
    }
    float acc = acc0 + acc1;

    // Wave-64 reduction
    #pragma unroll
    for (int off = 32; off > 0; off >>= 1)
        acc += __shfl_down(acc, off);

    __shared__ float smem[4];   // 256 threads = 4 waves
    const int lane = threadIdx.x & 63;
    const int wid  = threadIdx.x >> 6;
    if (lane == 0) smem[wid] = acc;
    __syncthreads();
    if (threadIdx.x == 0) {
        float t = smem[0] + smem[1] + smem[2] + smem[3];
        atomicAdd(out, t);
    }
}

extern "C" void kernel_launch(void* const* d_in, const int* in_sizes, int n_in,
                              void* d_out, int out_size, void* d_ws, size_t ws_size,
                              hipStream_t stream) {
    const float4* inputs  = (const float4*)d_in[0];
    const float4* targets = (const float4*)d_in[1];
    const float4* maxlv   = (const float4*)d_in[2];
    const float4* minlv   = (const float4*)d_in[3];
    float* out = (float*)d_out;

    const int nrows = in_sizes[1] / SIZE;      // N = 262144

    hipMemsetAsync(out, 0, sizeof(float), stream);

    const int block = 256;
    const int grid  = 2048;    // rstride = 16384 -> exactly 16 rows/thread
    probloss_kernel<<<grid, block, 0, stream>>>(inputs, targets, maxlv, minlv,
                                                out, nrows);
}

// Round 4
// 75.507 us; speedup vs baseline: 1.1361x; 1.1361x over previous
//
#include <hip/hip_runtime.h>
#include <hip/hip_bf16.h>

#define SIZE 128
#define NBLOCKS 8192

// var = e^b + 1/s, s = e^{-a} + e^{-lv};  inv_var = s/(e^b*s+1);
// sum(logvar) over a group = -log(prod inv_var)   [range-safe for groups of 4]
__global__ __launch_bounds__(256) void probloss_partial(
    const float4* __restrict__ inputs,    // (N, 256): 64 float4/row
    const float4* __restrict__ targets,   // (N, 128): 32 float4/row
    const float4* __restrict__ maxlv,     // 32 float4
    const float4* __restrict__ minlv,     // 32 float4
    float* __restrict__ part,             // NBLOCKS partials
    int nrows)
{
    const int gtid    = blockIdx.x * blockDim.x + threadIdx.x;
    const int cg      = gtid & 31;        // fixed column group
    const int row0    = gtid >> 5;
    const int rstride = (gridDim.x * blockDim.x) >> 5;   // 65536

    float4 a = maxlv[cg];
    float4 b = minlv[cg];
    float ena[4], eb[4];
    #pragma unroll
    for (int k = 0; k < 4; ++k) {
        ena[k] = __expf(-(&a.x)[k]);
        eb[k]  = __expf((&b.x)[k]);
    }

    float acc = 0.0f;
    for (int r = row0; r < nrows; r += rstride) {
        float4 m  = inputs[r * 64 + cg];
        float4 lv = inputs[r * 64 + 32 + cg];
        float4 tg = targets[r * 32 + cg];

        float prod = 1.0f;
        #pragma unroll
        for (int k = 0; k < 4; ++k) {
            float d   = (&m.x)[k] - (&tg.x)[k];
            float t   = __expf(-(&lv.x)[k]);               // v_exp_f32
            float s   = ena[k] + t;
            float u   = __builtin_fmaf(eb[k], s, 1.0f);
            float inv = s * __builtin_amdgcn_rcpf(u);      // v_rcp_f32
            acc  += d * d * inv;
            prod *= inv;
        }
        acc -= __logf(prod);                               // one log per 4 elems
    }

    // Wave-64 reduction
    #pragma unroll
    for (int off = 32; off > 0; off >>= 1)
        acc += __shfl_down(acc, off);

    __shared__ float smem[4];
    const int lane = threadIdx.x & 63;
    const int wid  = threadIdx.x >> 6;
    if (lane == 0) smem[wid] = acc;
    __syncthreads();
    if (threadIdx.x == 0)
        part[blockIdx.x] = smem[0] + smem[1] + smem[2] + smem[3];
}

__global__ __launch_bounds__(256) void probloss_final(
    const float4* __restrict__ part, float* __restrict__ out)
{
    // NBLOCKS floats = NBLOCKS/4 float4; 256 threads
    float acc = 0.0f;
    for (int i = threadIdx.x; i < NBLOCKS / 4; i += 256) {
        float4 v = part[i];
        acc += (v.x + v.y) + (v.z + v.w);
    }
    #pragma unroll
    for (int off = 32; off > 0; off >>= 1)
        acc += __shfl_down(acc, off);

    __shared__ float smem[4];
    const int lane = threadIdx.x & 63;
    const int wid  = threadIdx.x >> 6;
    if (lane == 0) smem[wid] = acc;
    __syncthreads();
    if (threadIdx.x == 0)
        out[0] = smem[0] + smem[1] + smem[2] + smem[3];
}

extern "C" void kernel_launch(void* const* d_in, const int* in_sizes, int n_in,
                              void* d_out, int out_size, void* d_ws, size_t ws_size,
                              hipStream_t stream) {
    const float4* inputs  = (const float4*)d_in[0];
    const float4* targets = (const float4*)d_in[1];
    const float4* maxlv   = (const float4*)d_in[2];
    const float4* minlv   = (const float4*)d_in[3];
    float* out  = (float*)d_out;
    float* part = (float*)d_ws;

    const int nrows = in_sizes[1] / SIZE;      // N = 262144

    probloss_partial<<<NBLOCKS, 256, 0, stream>>>(inputs, targets, maxlv, minlv,
                                                  part, nrows);
    probloss_final<<<1, 256, 0, stream>>>((const float4*)part, out);
}